// Round 11
// baseline (2497.115 us; speedup 1.0000x reference)
//
#include <hip/hip_runtime.h>
#include <hip/hip_fp16.h>

// ---------------------------------------------------------------------------
// sglayer: k=4 iterations of SpMM (COO segment-sum) then Linear(128->128).
// CSR build (bucket-native): prep -> phase A bucket partition -> phase B
// per-bucket LDS counting sort by (row, col-phase) -> rptr8 + byte-offset
// cols + fp16 weights.
// SpMM: column-phase-banded persistent kernel, 4-row-interleaved predicated
// inner loop (4 outstanding gathers/wave) so the ~3.2MB active band stays
// L2-resident per XCD AND the miss pipeline stays full.
// Linear: MFMA 16x16x32 f16.
// ---------------------------------------------------------------------------

#define F 128
#define CH 2048          // edges staged per block in phase A
#define MAXB 256         // max coarse buckets (N <= 131072)
#define RB_LOG 9         // rows per bucket = 512
#define RB (1 << RB_LOG)
#define CAPB 17408       // bucket region capacity (mean 16384, +8 sigma)
#define PH 8             // column phases
#define KEYS (RB * PH)   // 4096 sort keys per bucket
#define RW 24            // rows per wave in persistent SpMM
#define NG 6             // groups of 4 rows

typedef _Float16 half8 __attribute__((ext_vector_type(8)));
typedef float f32x4 __attribute__((ext_vector_type(4)));

// ---- prep: zero bcnt (block nwb) + W -> fp16 (blocks 0..nwb-1) -----------
__global__ void prep_kernel(const float* __restrict__ W, __half* __restrict__ Wh,
                            int nw, int* __restrict__ bcnt, int nwb) {
  int blk = blockIdx.x;
  if (blk == nwb) {
    int t = threadIdx.x;
    if (t < MAXB) bcnt[t] = 0;
  } else {
    int i = blk * 256 + threadIdx.x;
    if (i < nw) Wh[i] = __float2half(W[i]);
  }
}

// ---- Phase A: LDS-staged partition into fixed-capacity bucket regions ----
// mid[b*CAPB + k] entry: ((row & 511) << 17) | col , weight fp32 bits
__global__ __launch_bounds__(256) void bucket_scatter(
    const int* __restrict__ erow, const int* __restrict__ ecol,
    const float* __restrict__ ew, int* __restrict__ bcnt,
    int2* __restrict__ mid, int e, int nb) {
  __shared__ int  rowv[CH];                // 8 KB raw rows
  __shared__ int2 cw[CH];                  // 16 KB raw (col, wbits)
  __shared__ int2 stage[CH];               // 16 KB bucket-grouped
  __shared__ unsigned short sbid[CH];      // 4 KB
  __shared__ int cnt[MAXB], lstart[MAXB], gbase[MAXB], cnt2[MAXB];
  __shared__ int ps[256];
  int tid = threadIdx.x;
  int base = blockIdx.x * CH;
  int tot = e - base; if (tot > CH) tot = CH;
  for (int t = tid; t < nb; t += 256) { cnt[t] = 0; cnt2[t] = 0; }
  __syncthreads();
  for (int j = tid; j < tot; j += 256) {
    int i = base + j;
    int r = erow[i];
    rowv[j] = r;
    cw[j] = make_int2(ecol[i], __float_as_int(ew[i]));
    atomicAdd(&cnt[r >> RB_LOG], 1);
  }
  __syncthreads();
  int v = (tid < nb) ? cnt[tid] : 0;
  ps[tid] = v;
  __syncthreads();
  for (int off = 1; off < 256; off <<= 1) {
    int u = (tid >= off) ? ps[tid - off] : 0;
    __syncthreads();
    ps[tid] += u;
    __syncthreads();
  }
  if (tid < nb) lstart[tid] = ps[tid] - v;
  __syncthreads();
  for (int t = tid; t < nb; t += 256)
    if (cnt[t] > 0) gbase[t] = atomicAdd(&bcnt[t], cnt[t]);
  __syncthreads();
  for (int j = tid; j < tot; j += 256) {
    int r = rowv[j];
    int bb = r >> RB_LOG;
    int k = atomicAdd(&cnt2[bb], 1);
    int p = lstart[bb] + k;
    stage[p] = make_int2(((r & (RB - 1)) << 17) | cw[j].x, cw[j].y);
    sbid[p] = (unsigned short)bb;
  }
  __syncthreads();
  for (int j = tid; j < tot; j += 256) {   // coalesced bucket runs
    int bb = sbid[j];
    mid[(size_t)bb * CAPB + gbase[bb] + (j - lstart[bb])] = stage[j];
  }
}

// ---- Phase B: per-bucket counting sort by (row, col-phase) ---------------
// Emits rptr8[(r<<3)+s] segment starts, byte-offset cols, fp16 weights.
__global__ __launch_bounds__(256) void csr_sort(
    const int2* __restrict__ mid, const int* __restrict__ bcnt,
    int* __restrict__ rptr8, int* __restrict__ ecols, __half* __restrict__ ewh,
    int n, int nb, unsigned minv8) {
  __shared__ int cnt[KEYS];                // 16 KB: counts -> offsets/cursor
  __shared__ int psum[256];                // 1 KB
  __shared__ int2 st[CAPB];                // 136 KB
  int b = blockIdx.x, tid = threadIdx.x;
  int r0 = b << RB_LOG;
  int r1 = r0 + RB; if (r1 > n) r1 = n;
  int nr = r1 - r0;
  int cntE = bcnt[b];
  const int2* src = mid + (size_t)b * CAPB;

  // base = sum of bcnt[t < b]
  psum[tid] = (tid < b) ? bcnt[tid] : 0;
  __syncthreads();
  for (int off = 128; off > 0; off >>= 1) {
    if (tid < off) psum[tid] += psum[tid + off];
    __syncthreads();
  }
  int bas = psum[0];
  __syncthreads();

  for (int t = tid; t < KEYS; t += 256) cnt[t] = 0;
  __syncthreads();
  for (int i = tid; i < cntE; i += 256) {
    int2 ed = src[i];
    int rl  = ((unsigned)ed.x) >> 17;
    int col = ed.x & 0x1FFFF;
    unsigned ph = __umulhi((unsigned)col, minv8);
    if (ph > PH - 1) ph = PH - 1;
    atomicAdd(&cnt[(rl << 3) | ph], 1);
  }
  __syncthreads();
  // in-place exclusive scan of cnt[0..4096): 16 per thread
  int v[16]; int sum = 0;
#pragma unroll
  for (int t = 0; t < 16; ++t) { v[t] = cnt[tid * 16 + t]; sum += v[t]; }
  psum[tid] = sum;
  __syncthreads();
  for (int off = 1; off < 256; off <<= 1) {
    int u = (tid >= off) ? psum[tid - off] : 0;
    __syncthreads();
    psum[tid] += u;
    __syncthreads();
  }
  int run = (tid > 0) ? psum[tid - 1] : 0;
#pragma unroll
  for (int t = 0; t < 16; ++t) { cnt[tid * 16 + t] = run; run += v[t]; }
  __syncthreads();
  // write rptr8 before cursor destruction
  for (int t = tid; t < nr * PH; t += 256) rptr8[(r0 << 3) + t] = bas + cnt[t];
  if (b == nb - 1 && tid == 0) rptr8[(size_t)n << 3] = bas + cntE;
  // counting sort into LDS (cnt doubles as cursor); col -> byte offset
  for (int i = tid; i < cntE; i += 256) {
    int2 ed = src[i];
    int rl  = ((unsigned)ed.x) >> 17;
    int col = ed.x & 0x1FFFF;
    unsigned ph = __umulhi((unsigned)col, minv8);
    if (ph > PH - 1) ph = PH - 1;
    int p = atomicAdd(&cnt[(rl << 3) | ph], 1);
    st[p] = make_int2(col << 8, ed.y);
  }
  __syncthreads();
  for (int i = tid; i < cntE; i += 256) {
    int2 ed = st[i];
    ecols[bas + i] = ed.x;
    ewh[bas + i]   = __float2half(__int_as_float(ed.y));
  }
}

// ---- persistent banded SpMM, 4-row-interleaved predicated inner loop -----
// grid = ceil(N/(4*RW)) co-resident blocks; wave owns RW rows as NG groups
// of 4; per (group, phase) a max-length loop keeps 4 gathers in flight.
__global__ __launch_bounds__(256, 4) void spmm_persist(
    const int* __restrict__ rptr8, const int* __restrict__ ecols,
    const __half* __restrict__ ewh, const __half* __restrict__ xin,
    __half* __restrict__ xout, int n) {
  int lane = threadIdx.x & 63;
  int wid = (blockIdx.x << 2) + (threadIdx.x >> 6);
  int r0 = wid * RW;
  const char* xb = (const char*)xin;
  float2 acc[RW];
#pragma unroll
  for (int j = 0; j < RW; ++j) acc[j] = make_float2(0.f, 0.f);

  for (int s = 0; s < PH; ++s) {
#pragma unroll
    for (int g = 0; g < NG; ++g) {
      int rb = r0 + g * 4;
      int rr0 = rb + 0 < n ? rb + 0 : n - 1;
      int rr1 = rb + 1 < n ? rb + 1 : n - 1;
      int rr2 = rb + 2 < n ? rb + 2 : n - 1;
      int rr3 = rb + 3 < n ? rb + 3 : n - 1;
      int b0 = rptr8[(rr0 << 3) + s], E0 = rptr8[(rr0 << 3) + s + 1];
      int b1 = rptr8[(rr1 << 3) + s], E1 = rptr8[(rr1 << 3) + s + 1];
      int b2 = rptr8[(rr2 << 3) + s], E2 = rptr8[(rr2 << 3) + s + 1];
      int b3 = rptr8[(rr3 << 3) + s], E3 = rptr8[(rr3 << 3) + s + 1];
      if (rb + 0 >= n) E0 = b0;
      if (rb + 1 >= n) E1 = b1;
      if (rb + 2 >= n) E2 = b2;
      if (rb + 3 >= n) E3 = b3;
      int K = max(max(E0 - b0, E1 - b1), max(E2 - b2, E3 - b3));
      float2 A0 = acc[g * 4 + 0], A1 = acc[g * 4 + 1];
      float2 A2 = acc[g * 4 + 2], A3 = acc[g * 4 + 3];
      for (int k = 0; k < K; ++k) {
        int i0 = b0 + k, i1 = b1 + k, i2 = b2 + k, i3 = b3 + k;
        bool v0 = i0 < E0, v1 = i1 < E1, v2 = i2 < E2, v3 = i3 < E3;
        int ci0 = v0 ? i0 : 0, ci1 = v1 ? i1 : 0;
        int ci2 = v2 ? i2 : 0, ci3 = v3 ? i3 : 0;
        int c0 = ecols[ci0], c1 = ecols[ci1];
        int c2 = ecols[ci2], c3 = ecols[ci3];
        union { int i; __half2 h2; } u0, u1, u2, u3;
        u0.i = *(const int*)(xb + (size_t)(unsigned)c0 + (lane << 2));
        u1.i = *(const int*)(xb + (size_t)(unsigned)c1 + (lane << 2));
        u2.i = *(const int*)(xb + (size_t)(unsigned)c2 + (lane << 2));
        u3.i = *(const int*)(xb + (size_t)(unsigned)c3 + (lane << 2));
        float w0 = v0 ? __half2float(ewh[ci0]) : 0.f;
        float w1 = v1 ? __half2float(ewh[ci1]) : 0.f;
        float w2 = v2 ? __half2float(ewh[ci2]) : 0.f;
        float w3 = v3 ? __half2float(ewh[ci3]) : 0.f;
        float2 f0 = __half22float2(u0.h2);
        float2 f1 = __half22float2(u1.h2);
        float2 f2 = __half22float2(u2.h2);
        float2 f3 = __half22float2(u3.h2);
        A0.x = fmaf(w0, f0.x, A0.x); A0.y = fmaf(w0, f0.y, A0.y);
        A1.x = fmaf(w1, f1.x, A1.x); A1.y = fmaf(w1, f1.y, A1.y);
        A2.x = fmaf(w2, f2.x, A2.x); A2.y = fmaf(w2, f2.y, A2.y);
        A3.x = fmaf(w3, f3.x, A3.x); A3.y = fmaf(w3, f3.y, A3.y);
      }
      acc[g * 4 + 0] = A0; acc[g * 4 + 1] = A1;
      acc[g * 4 + 2] = A2; acc[g * 4 + 3] = A3;
    }
  }
#pragma unroll
  for (int j = 0; j < RW; ++j) {
    int r = r0 + j;
    if (r < n)
      *(__half2*)((char*)xout + ((size_t)r << 8) + (lane << 2)) =
          __float22half2_rn(acc[j]);
  }
}

__global__ void f32_to_f16(const float2* __restrict__ in, __half2* __restrict__ out, int n2) {
  int i = blockIdx.x * blockDim.x + threadIdx.x;
  if (i < n2) out[i] = __float22half2_rn(in[i]);
}

// ---- Linear via MFMA 16x16x32 f16: out = X(fp16) @ Wh^T + b --------------
__global__ __launch_bounds__(256) void linear_mfma(
    const __half* __restrict__ xin, const __half* __restrict__ Wh,
    const float* __restrict__ b, float* __restrict__ out, int n) {
  int lane = threadIdx.x & 63;
  int wv   = threadIdx.x >> 6;
  int rbase = blockIdx.x * 64 + wv * 16;
  if (rbase >= n) return;
  int arow = rbase + (lane & 15);
  if (arow >= n) arow = n - 1;               // clamp; padded rows discarded
  int koff = (lane >> 4) * 8;                // 8 consecutive k per lane

  half8 a0 = *(const half8*)(xin + (size_t)arow * F + 0  + koff);
  half8 a1 = *(const half8*)(xin + (size_t)arow * F + 32 + koff);
  half8 a2 = *(const half8*)(xin + (size_t)arow * F + 64 + koff);
  half8 a3 = *(const half8*)(xin + (size_t)arow * F + 96 + koff);

  int drow0 = rbase + (lane >> 4) * 4;       // D: row=(l>>4)*4+m, col=l&15
  int dcol  = lane & 15;
#pragma unroll
  for (int jt = 0; jt < 8; ++jt) {
    const __half* wrow = Wh + (size_t)(jt * 16 + (lane & 15)) * F + koff;
    half8 b0 = *(const half8*)(wrow + 0);
    half8 b1 = *(const half8*)(wrow + 32);
    half8 b2 = *(const half8*)(wrow + 64);
    half8 b3 = *(const half8*)(wrow + 96);
    f32x4 acc = {0.f, 0.f, 0.f, 0.f};
    acc = __builtin_amdgcn_mfma_f32_16x16x32_f16(a0, b0, acc, 0, 0, 0);
    acc = __builtin_amdgcn_mfma_f32_16x16x32_f16(a1, b1, acc, 0, 0, 0);
    acc = __builtin_amdgcn_mfma_f32_16x16x32_f16(a2, b2, acc, 0, 0, 0);
    acc = __builtin_amdgcn_mfma_f32_16x16x32_f16(a3, b3, acc, 0, 0, 0);
    float bias = b[jt * 16 + dcol];
#pragma unroll
    for (int m = 0; m < 4; ++m) {
      int r = drow0 + m;
      if (r < n) out[(size_t)r * F + jt * 16 + dcol] = acc[m] + bias;
    }
  }
}

extern "C" void kernel_launch(void* const* d_in, const int* in_sizes, int n_in,
                              void* d_out, int out_size, void* d_ws, size_t ws_size,
                              hipStream_t stream) {
  const float* x    = (const float*)d_in[0];
  const int*   erow = (const int*)d_in[1];
  const int*   ecol = (const int*)d_in[2];
  const float* ew   = (const float*)d_in[3];
  const float* W    = (const float*)d_in[4];
  const float* b    = (const float*)d_in[5];
  float* out = (float*)d_out;

  const int N = in_sizes[0] / F;
  const int E = in_sizes[1];

  char* ws = (char*)d_ws;
  size_t off = 0;
  int*    ecols = (int*)(ws + off);    off += (size_t)E * 4;
  __half* ewh   = (__half*)(ws + off); off += (size_t)E * 2;
  off = (off + 255) & ~(size_t)255;
  int*   rptr8  = (int*)(ws + off);    off += ((size_t)N * PH + 1) * 4;
  int*   bcnt   = (int*)(ws + off);    off += MAXB * 4;
  off = (off + 255) & ~(size_t)255;
  __half* Wh    = (__half*)(ws + off); off += (size_t)F * F * 2;
  off = (off + 255) & ~(size_t)255;
  // big region (51.2 MB): hosts mid (nb*CAPB int2 <= 27.3 MB) during the CSR
  // build, then the fp16 ping-pong buffers A,B (25.6 MB each). mid is fully
  // consumed by csr_sort before f32_to_f16 writes bufB (stream-serial).
  __half* bufA = (__half*)(ws + off);
  __half* bufB = (__half*)(ws + off + (size_t)N * F * 2);
  int2*   mid  = (int2*)bufA;

  const int BK = 256;
  int nb = (N + RB - 1) >> RB_LOG;     // 512-row buckets (<= MAXB)
  int nwb = (F * F + BK - 1) / BK;     // W-conversion blocks
  // phase selector: ph = floor(col * PH / N) via umulhi
  unsigned minv8 = (unsigned)(((unsigned long long)PH << 32) / (unsigned)N + 1);

  // --- prep (zero bcnt + W->fp16) and bucket-native CSR build
  prep_kernel<<<nwb + 1, BK, 0, stream>>>(W, Wh, F * F, bcnt, nwb);
  bucket_scatter<<<(E + CH - 1) / CH, 256, 0, stream>>>(erow, ecol, ew, bcnt, mid, E, nb);
  csr_sort<<<nb, 256, 0, stream>>>(mid, bcnt, rptr8, ecols, ewh, N, nb, minv8);

  // --- convert x to fp16, then 4 persistent SpMM iterations
  int n2 = N * (F / 2);
  f32_to_f16<<<(n2 + BK - 1) / BK, BK, 0, stream>>>((const float2*)x, (__half2*)bufB, n2);
  int pgrid = (N + 4 * RW - 1) / (4 * RW);   // ~1042 blocks, ~all co-resident
  spmm_persist<<<pgrid, 256, 0, stream>>>(rptr8, ecols, ewh, bufB, bufA, N);
  spmm_persist<<<pgrid, 256, 0, stream>>>(rptr8, ecols, ewh, bufA, bufB, N);
  spmm_persist<<<pgrid, 256, 0, stream>>>(rptr8, ecols, ewh, bufB, bufA, N);
  spmm_persist<<<pgrid, 256, 0, stream>>>(rptr8, ecols, ewh, bufA, bufB, N);

  // --- Linear: bufB (fp16) @ Wh^T + b -> out (fp32), via MFMA
  linear_mfma<<<(N + 63) / 64, 256, 0, stream>>>(bufB, Wh, b, out, N);
}

// Round 12
// 576.070 us; speedup vs baseline: 4.3347x; 4.3347x over previous
//
#include <hip/hip_runtime.h>
#include <hip/hip_fp16.h>

// ---------------------------------------------------------------------------
// sglayer: k=4 iterations of SpMM (COO segment-sum) then Linear(128->128).
// CSR build (bucket-native): prep (zero bcnt + W->fp16) -> phase A bucket
// partition -> phase B per-bucket LDS sort -> split col[byteoff]/w[fp16].
// SpMM: fp16 storage / fp32 accumulate, 1 wave/row, WIDE gathers
// (dwordx4/lane, lane-quarter per edge) unrolled to 4 in-flight gathers
// (16 edges/iter) to fill the L2-miss latency pipe. Linear: MFMA 16x16x32.
// ---------------------------------------------------------------------------

#define F 128
#define CH 2048          // edges staged per block in phase A
#define MAXB 256         // max coarse buckets (N <= 131072)
#define RB_LOG 9         // rows per bucket = 512
#define RB (1 << RB_LOG)
#define CAPB 18432       // bucket region capacity (mean 16384, +16 sigma)

typedef _Float16 half8 __attribute__((ext_vector_type(8)));
typedef float f32x4 __attribute__((ext_vector_type(4)));

// ---- prep: zero bcnt (block nwb) + W -> fp16 (blocks 0..nwb-1) -----------
__global__ void prep_kernel(const float* __restrict__ W, __half* __restrict__ Wh,
                            int nw, int* __restrict__ bcnt, int nwb) {
  int blk = blockIdx.x;
  if (blk == nwb) {
    int t = threadIdx.x;
    if (t < MAXB) bcnt[t] = 0;
  } else {
    int i = blk * 256 + threadIdx.x;
    if (i < nw) Wh[i] = __float2half(W[i]);
  }
}

// ---- Phase A: LDS-staged partition into fixed-capacity bucket regions ----
// mid[b*CAPB + k] entry: ((row & 511) << 17) | col , weight fp32 bits
__global__ __launch_bounds__(256) void bucket_scatter(
    const int* __restrict__ erow, const int* __restrict__ ecol,
    const float* __restrict__ ew, int* __restrict__ bcnt,
    int2* __restrict__ mid, int e, int nb) {
  __shared__ int  rowv[CH];                // 8 KB raw rows
  __shared__ int2 cw[CH];                  // 16 KB raw (col, wbits)
  __shared__ int2 stage[CH];               // 16 KB bucket-grouped
  __shared__ unsigned short sbid[CH];      // 4 KB
  __shared__ int cnt[MAXB], lstart[MAXB], gbase[MAXB], cnt2[MAXB];
  __shared__ int ps[256];
  int tid = threadIdx.x;
  int base = blockIdx.x * CH;
  int tot = e - base; if (tot > CH) tot = CH;
  for (int t = tid; t < nb; t += 256) { cnt[t] = 0; cnt2[t] = 0; }
  __syncthreads();
  for (int j = tid; j < tot; j += 256) {
    int i = base + j;
    int r = erow[i];
    rowv[j] = r;
    cw[j] = make_int2(ecol[i], __float_as_int(ew[i]));
    atomicAdd(&cnt[r >> RB_LOG], 1);
  }
  __syncthreads();
  int v = (tid < nb) ? cnt[tid] : 0;
  ps[tid] = v;
  __syncthreads();
  for (int off = 1; off < 256; off <<= 1) {
    int u = (tid >= off) ? ps[tid - off] : 0;
    __syncthreads();
    ps[tid] += u;
    __syncthreads();
  }
  if (tid < nb) lstart[tid] = ps[tid] - v;
  __syncthreads();
  for (int t = tid; t < nb; t += 256)
    if (cnt[t] > 0) gbase[t] = atomicAdd(&bcnt[t], cnt[t]);
  __syncthreads();
  for (int j = tid; j < tot; j += 256) {
    int r = rowv[j];
    int bb = r >> RB_LOG;
    int k = atomicAdd(&cnt2[bb], 1);
    int p = lstart[bb] + k;
    stage[p] = make_int2(((r & (RB - 1)) << 17) | cw[j].x, cw[j].y);
    sbid[p] = (unsigned short)bb;
  }
  __syncthreads();
  for (int j = tid; j < tot; j += 256) {   // coalesced bucket runs
    int bb = sbid[j];
    mid[(size_t)bb * CAPB + gbase[bb] + (j - lstart[bb])] = stage[j];
  }
}

// ---- Phase B: per-bucket base reduce, LDS hist+scan (rptr), count sort ---
// outputs split arrays: ecols[i] = col byte-offset, ewh[i] = fp16 weight
__global__ __launch_bounds__(256) void csr_sort(
    const int2* __restrict__ mid, const int* __restrict__ bcnt,
    int* __restrict__ rptr, int* __restrict__ ecols, __half* __restrict__ ewh,
    int n, int nb) {
  __shared__ int rcnt[RB];                 // 2 KB
  __shared__ int rofs[RB];                 // 2 KB (exclusive ofs, then cursor)
  __shared__ int psum[256];                // 1 KB
  __shared__ int2 st[CAPB];                // 144 KB
  int b = blockIdx.x, tid = threadIdx.x;
  int r0 = b << RB_LOG;
  int r1 = r0 + RB; if (r1 > n) r1 = n;
  int nr = r1 - r0;
  int cnt = bcnt[b];
  const int2* src = mid + (size_t)b * CAPB;

  psum[tid] = (tid < b && tid < nb) ? bcnt[tid] : 0;
  __syncthreads();
  for (int off = 128; off > 0; off >>= 1) {
    if (tid < off) psum[tid] += psum[tid + off];
    __syncthreads();
  }
  int bas = psum[0];
  __syncthreads();

  for (int r = tid; r < RB; r += 256) rcnt[r] = 0;
  __syncthreads();
  for (int i = tid; i < cnt; i += 256)
    atomicAdd(&rcnt[((unsigned)src[i].x) >> 17], 1);
  __syncthreads();
  int s2 = rcnt[2 * tid] + rcnt[2 * tid + 1];
  psum[tid] = s2;
  __syncthreads();
  for (int off = 1; off < 256; off <<= 1) {
    int u = (tid >= off) ? psum[tid - off] : 0;
    __syncthreads();
    psum[tid] += u;
    __syncthreads();
  }
  int ex = (tid > 0) ? psum[tid - 1] : 0;
  rofs[2 * tid]     = ex;
  rofs[2 * tid + 1] = ex + rcnt[2 * tid];
  __syncthreads();
  for (int r = tid; r < nr; r += 256) rptr[r0 + r] = bas + rofs[r];
  if (b == nb - 1 && tid == 0) rptr[n] = bas + cnt;
  for (int i = tid; i < cnt; i += 256) {
    int2 ed = src[i];
    int rl  = ((unsigned)ed.x) >> 17;
    int col = ed.x & 0x1FFFF;
    int p = atomicAdd(&rofs[rl], 1);
    st[p] = make_int2(col, ed.y);
  }
  __syncthreads();
  for (int i = tid; i < cnt; i += 256) {
    int2 ed = st[i];
    ecols[bas + i] = ed.x << 8;          // byte offset into fp16 x-table
    ewh[bas + i]   = __float2half(__int_as_float(ed.y));
  }
}

// ---- SpMM: wide gathers, 4 in flight (16 edges/iter) ---------------------
// lane-quarter q = lane>>4 owns edge i+4k+q; lane holds 8 feats (fl=lane&15).
__global__ __launch_bounds__(256) void spmm_kernel(
    const int* __restrict__ rptr, const int* __restrict__ ecols,
    const __half* __restrict__ ewh,
    const __half* __restrict__ xin, __half* __restrict__ xout, int n) {
  int lane = threadIdx.x & 63;
  int q  = lane >> 4;             // edge within group-of-4
  int fl = lane & 15;             // 16 B feature chunk within 256 B row
  int row = (blockIdx.x << 2) + (threadIdx.x >> 6);
  if (row >= n) return;
  int s = rptr[row], e = rptr[row + 1];
  float a00 = 0.f, a01 = 0.f, a02 = 0.f, a03 = 0.f;
  float a04 = 0.f, a05 = 0.f, a06 = 0.f, a07 = 0.f;
  float b00 = 0.f, b01 = 0.f, b02 = 0.f, b03 = 0.f;
  float b04 = 0.f, b05 = 0.f, b06 = 0.f, b07 = 0.f;
  float c00 = 0.f, c01 = 0.f, c02 = 0.f, c03 = 0.f;
  float c04 = 0.f, c05 = 0.f, c06 = 0.f, c07 = 0.f;
  float d00 = 0.f, d01 = 0.f, d02 = 0.f, d03 = 0.f;
  float d04 = 0.f, d05 = 0.f, d06 = 0.f, d07 = 0.f;
  const char* xb = (const char*)xin;
  union V { int4 i4; __half2 h2[4]; };

#define UNPACK_FMA(U, W, P)                                                   \
  {                                                                           \
    float2 f0 = __half22float2((U).h2[0]);                                    \
    float2 f1 = __half22float2((U).h2[1]);                                    \
    float2 f2 = __half22float2((U).h2[2]);                                    \
    float2 f3 = __half22float2((U).h2[3]);                                    \
    P##0 = fmaf((W), f0.x, P##0); P##1 = fmaf((W), f0.y, P##1);               \
    P##2 = fmaf((W), f1.x, P##2); P##3 = fmaf((W), f1.y, P##3);               \
    P##4 = fmaf((W), f2.x, P##4); P##5 = fmaf((W), f2.y, P##5);               \
    P##6 = fmaf((W), f3.x, P##6); P##7 = fmaf((W), f3.y, P##7);               \
  }

  int i = s;
  for (; i + 15 < e; i += 16) {    // 16 edges = 4 wide gathers in flight
    int   ca = ecols[i + q];
    int   cb = ecols[i + 4 + q];
    int   cc = ecols[i + 8 + q];
    int   cd = ecols[i + 12 + q];
    float wa = __half2float(ewh[i + q]);
    float wb = __half2float(ewh[i + 4 + q]);
    float wc = __half2float(ewh[i + 8 + q]);
    float wd = __half2float(ewh[i + 12 + q]);
    V va, vb, vc, vd;
    va.i4 = *(const int4*)(xb + (size_t)(unsigned)ca + (fl << 4));
    vb.i4 = *(const int4*)(xb + (size_t)(unsigned)cb + (fl << 4));
    vc.i4 = *(const int4*)(xb + (size_t)(unsigned)cc + (fl << 4));
    vd.i4 = *(const int4*)(xb + (size_t)(unsigned)cd + (fl << 4));
    UNPACK_FMA(va, wa, a0);
    UNPACK_FMA(vb, wb, b0);
    UNPACK_FMA(vc, wc, c0);
    UNPACK_FMA(vd, wd, d0);
  }
  for (; i + 7 < e; i += 8) {      // 8 edges = 2 wide gathers
    int   ca = ecols[i + q];
    int   cb = ecols[i + 4 + q];
    float wa = __half2float(ewh[i + q]);
    float wb = __half2float(ewh[i + 4 + q]);
    V va, vb;
    va.i4 = *(const int4*)(xb + (size_t)(unsigned)ca + (fl << 4));
    vb.i4 = *(const int4*)(xb + (size_t)(unsigned)cb + (fl << 4));
    UNPACK_FMA(va, wa, a0);
    UNPACK_FMA(vb, wb, b0);
  }
  for (; i < e; i += 4) {          // tail groups of <=4 edges (predicated)
    int idx = i + q;
    bool ok = idx < e;
    int   c = ecols[ok ? idx : e - 1];
    float w = ok ? __half2float(ewh[idx]) : 0.f;
    V v;
    v.i4 = *(const int4*)(xb + (size_t)(unsigned)c + (fl << 4));
    UNPACK_FMA(v, w, a0);
  }
#undef UNPACK_FMA

  a00 += b00 + c00 + d00; a01 += b01 + c01 + d01;
  a02 += b02 + c02 + d02; a03 += b03 + c03 + d03;
  a04 += b04 + c04 + d04; a05 += b05 + c05 + d05;
  a06 += b06 + c06 + d06; a07 += b07 + c07 + d07;
#define RED(X) X += __shfl_xor(X, 16, 64); X += __shfl_xor(X, 32, 64);
  RED(a00) RED(a01) RED(a02) RED(a03) RED(a04) RED(a05) RED(a06) RED(a07)
#undef RED
  if (q == 0) {
    union V o;
    o.h2[0] = __float22half2_rn(make_float2(a00, a01));
    o.h2[1] = __float22half2_rn(make_float2(a02, a03));
    o.h2[2] = __float22half2_rn(make_float2(a04, a05));
    o.h2[3] = __float22half2_rn(make_float2(a06, a07));
    *(int4*)((char*)xout + ((size_t)row << 8) + (fl << 4)) = o.i4;
  }
}

__global__ void f32_to_f16(const float2* __restrict__ in, __half2* __restrict__ out, int n2) {
  int i = blockIdx.x * blockDim.x + threadIdx.x;
  if (i < n2) out[i] = __float22half2_rn(in[i]);
}

// ---- Linear via MFMA 16x16x32 f16: out = X(fp16) @ Wh^T + b --------------
__global__ __launch_bounds__(256) void linear_mfma(
    const __half* __restrict__ xin, const __half* __restrict__ Wh,
    const float* __restrict__ b, float* __restrict__ out, int n) {
  int lane = threadIdx.x & 63;
  int wv   = threadIdx.x >> 6;
  int rbase = blockIdx.x * 64 + wv * 16;
  if (rbase >= n) return;
  int arow = rbase + (lane & 15);
  if (arow >= n) arow = n - 1;               // clamp; padded rows discarded
  int koff = (lane >> 4) * 8;                // 8 consecutive k per lane

  half8 a0 = *(const half8*)(xin + (size_t)arow * F + 0  + koff);
  half8 a1 = *(const half8*)(xin + (size_t)arow * F + 32 + koff);
  half8 a2 = *(const half8*)(xin + (size_t)arow * F + 64 + koff);
  half8 a3 = *(const half8*)(xin + (size_t)arow * F + 96 + koff);

  int drow0 = rbase + (lane >> 4) * 4;       // D: row=(l>>4)*4+m, col=l&15
  int dcol  = lane & 15;
#pragma unroll
  for (int jt = 0; jt < 8; ++jt) {
    const __half* wrow = Wh + (size_t)(jt * 16 + (lane & 15)) * F + koff;
    half8 b0 = *(const half8*)(wrow + 0);
    half8 b1 = *(const half8*)(wrow + 32);
    half8 b2 = *(const half8*)(wrow + 64);
    half8 b3 = *(const half8*)(wrow + 96);
    f32x4 acc = {0.f, 0.f, 0.f, 0.f};
    acc = __builtin_amdgcn_mfma_f32_16x16x32_f16(a0, b0, acc, 0, 0, 0);
    acc = __builtin_amdgcn_mfma_f32_16x16x32_f16(a1, b1, acc, 0, 0, 0);
    acc = __builtin_amdgcn_mfma_f32_16x16x32_f16(a2, b2, acc, 0, 0, 0);
    acc = __builtin_amdgcn_mfma_f32_16x16x32_f16(a3, b3, acc, 0, 0, 0);
    float bias = b[jt * 16 + dcol];
#pragma unroll
    for (int m = 0; m < 4; ++m) {
      int r = drow0 + m;
      if (r < n) out[(size_t)r * F + jt * 16 + dcol] = acc[m] + bias;
    }
  }
}

extern "C" void kernel_launch(void* const* d_in, const int* in_sizes, int n_in,
                              void* d_out, int out_size, void* d_ws, size_t ws_size,
                              hipStream_t stream) {
  const float* x    = (const float*)d_in[0];
  const int*   erow = (const int*)d_in[1];
  const int*   ecol = (const int*)d_in[2];
  const float* ew   = (const float*)d_in[3];
  const float* W    = (const float*)d_in[4];
  const float* b    = (const float*)d_in[5];
  float* out = (float*)d_out;

  const int N = in_sizes[0] / F;
  const int E = in_sizes[1];

  char* ws = (char*)d_ws;
  size_t off = 0;
  int*    ecols = (int*)(ws + off);    off += (size_t)E * 4;
  __half* ewh   = (__half*)(ws + off); off += (size_t)E * 2;
  off = (off + 255) & ~(size_t)255;
  int*   rptr   = (int*)(ws + off);    off += (size_t)(N + 1) * 4;
  int*   bcnt   = (int*)(ws + off);    off += MAXB * 4;
  off = (off + 255) & ~(size_t)255;
  __half* Wh    = (__half*)(ws + off); off += (size_t)F * F * 2;
  off = (off + 255) & ~(size_t)255;
  // big region (51.2 MB): hosts mid (nb*CAPB int2 <= 28.9 MB) during the CSR
  // build, then the fp16 ping-pong buffers A,B (25.6 MB each). mid is fully
  // consumed by csr_sort before f32_to_f16 writes bufB (stream-serial).
  __half* bufA = (__half*)(ws + off);
  __half* bufB = (__half*)(ws + off + (size_t)N * F * 2);
  int2*   mid  = (int2*)bufA;

  const int BK = 256;
  int nb = (N + RB - 1) >> RB_LOG;     // 512-row buckets (<= MAXB)
  int nwb = (F * F + BK - 1) / BK;     // W-conversion blocks

  // --- prep (zero bcnt + W->fp16) and bucket-native CSR build
  prep_kernel<<<nwb + 1, BK, 0, stream>>>(W, Wh, F * F, bcnt, nwb);
  bucket_scatter<<<(E + CH - 1) / CH, 256, 0, stream>>>(erow, ecol, ew, bcnt, mid, E, nb);
  csr_sort<<<nb, 256, 0, stream>>>(mid, bcnt, rptr, ecols, ewh, N, nb);

  // --- convert x to fp16, then 4 SpMM iterations (ping-pong B <-> A)
  int n2 = N * (F / 2);
  f32_to_f16<<<(n2 + BK - 1) / BK, BK, 0, stream>>>((const float2*)x, (__half2*)bufB, n2);
  int spmm_grid = (N + 3) / 4;
  spmm_kernel<<<spmm_grid, 256, 0, stream>>>(rptr, ecols, ewh, bufB, bufA, N);
  spmm_kernel<<<spmm_grid, 256, 0, stream>>>(rptr, ecols, ewh, bufA, bufB, N);
  spmm_kernel<<<spmm_grid, 256, 0, stream>>>(rptr, ecols, ewh, bufB, bufA, N);
  spmm_kernel<<<spmm_grid, 256, 0, stream>>>(rptr, ecols, ewh, bufA, bufB, N);

  // --- Linear: bufB (fp16) @ Wh^T + b -> out (fp32), via MFMA
  linear_mfma<<<(N + 63) / 64, 256, 0, stream>>>(bufB, Wh, b, out, N);
}

// Round 13
// 558.958 us; speedup vs baseline: 4.4674x; 1.0306x over previous
//
#include <hip/hip_runtime.h>
#include <hip/hip_fp16.h>

// ---------------------------------------------------------------------------
// sglayer: k=4 iterations of SpMM (COO segment-sum) then Linear(128->128).
// CSR build (bucket-native): prep (zero bcnt + W->fp16) -> phase A bucket
// partition -> phase B per-bucket LDS sort -> split col[byteoff]/w[fp16].
// SpMM: fp16 storage / fp32 accumulate, 1 wave/row, WIDE gathers
// (dwordx4/lane, lane-quarter per edge), 2 in flight (8 edges/iter) —
// empirically the sweet spot: the kernel sits on the per-CU miss-transaction
// rate wall (~49 misses/us/CU), so deeper unrolls only cost occupancy.
// Linear: MFMA 16x16x32 f16.
// ---------------------------------------------------------------------------

#define F 128
#define CH 2048          // edges staged per block in phase A
#define MAXB 256         // max coarse buckets (N <= 131072)
#define RB_LOG 9         // rows per bucket = 512
#define RB (1 << RB_LOG)
#define CAPB 18432       // bucket region capacity (mean 16384, +16 sigma)

typedef _Float16 half8 __attribute__((ext_vector_type(8)));
typedef float f32x4 __attribute__((ext_vector_type(4)));

// ---- prep: zero bcnt (block nwb) + W -> fp16 (blocks 0..nwb-1) -----------
__global__ void prep_kernel(const float* __restrict__ W, __half* __restrict__ Wh,
                            int nw, int* __restrict__ bcnt, int nwb) {
  int blk = blockIdx.x;
  if (blk == nwb) {
    int t = threadIdx.x;
    if (t < MAXB) bcnt[t] = 0;
  } else {
    int i = blk * 256 + threadIdx.x;
    if (i < nw) Wh[i] = __float2half(W[i]);
  }
}

// ---- Phase A: LDS-staged partition into fixed-capacity bucket regions ----
// mid[b*CAPB + k] entry: ((row & 511) << 17) | col , weight fp32 bits
__global__ __launch_bounds__(256) void bucket_scatter(
    const int* __restrict__ erow, const int* __restrict__ ecol,
    const float* __restrict__ ew, int* __restrict__ bcnt,
    int2* __restrict__ mid, int e, int nb) {
  __shared__ int  rowv[CH];                // 8 KB raw rows
  __shared__ int2 cw[CH];                  // 16 KB raw (col, wbits)
  __shared__ int2 stage[CH];               // 16 KB bucket-grouped
  __shared__ unsigned short sbid[CH];      // 4 KB
  __shared__ int cnt[MAXB], lstart[MAXB], gbase[MAXB], cnt2[MAXB];
  __shared__ int ps[256];
  int tid = threadIdx.x;
  int base = blockIdx.x * CH;
  int tot = e - base; if (tot > CH) tot = CH;
  for (int t = tid; t < nb; t += 256) { cnt[t] = 0; cnt2[t] = 0; }
  __syncthreads();
  for (int j = tid; j < tot; j += 256) {
    int i = base + j;
    int r = erow[i];
    rowv[j] = r;
    cw[j] = make_int2(ecol[i], __float_as_int(ew[i]));
    atomicAdd(&cnt[r >> RB_LOG], 1);
  }
  __syncthreads();
  int v = (tid < nb) ? cnt[tid] : 0;
  ps[tid] = v;
  __syncthreads();
  for (int off = 1; off < 256; off <<= 1) {
    int u = (tid >= off) ? ps[tid - off] : 0;
    __syncthreads();
    ps[tid] += u;
    __syncthreads();
  }
  if (tid < nb) lstart[tid] = ps[tid] - v;
  __syncthreads();
  for (int t = tid; t < nb; t += 256)
    if (cnt[t] > 0) gbase[t] = atomicAdd(&bcnt[t], cnt[t]);
  __syncthreads();
  for (int j = tid; j < tot; j += 256) {
    int r = rowv[j];
    int bb = r >> RB_LOG;
    int k = atomicAdd(&cnt2[bb], 1);
    int p = lstart[bb] + k;
    stage[p] = make_int2(((r & (RB - 1)) << 17) | cw[j].x, cw[j].y);
    sbid[p] = (unsigned short)bb;
  }
  __syncthreads();
  for (int j = tid; j < tot; j += 256) {   // coalesced bucket runs
    int bb = sbid[j];
    mid[(size_t)bb * CAPB + gbase[bb] + (j - lstart[bb])] = stage[j];
  }
}

// ---- Phase B: per-bucket base reduce, LDS hist+scan (rptr), count sort ---
// outputs split arrays: ecols[i] = col byte-offset, ewh[i] = fp16 weight
__global__ __launch_bounds__(256) void csr_sort(
    const int2* __restrict__ mid, const int* __restrict__ bcnt,
    int* __restrict__ rptr, int* __restrict__ ecols, __half* __restrict__ ewh,
    int n, int nb) {
  __shared__ int rcnt[RB];                 // 2 KB
  __shared__ int rofs[RB];                 // 2 KB (exclusive ofs, then cursor)
  __shared__ int psum[256];                // 1 KB
  __shared__ int2 st[CAPB];                // 144 KB
  int b = blockIdx.x, tid = threadIdx.x;
  int r0 = b << RB_LOG;
  int r1 = r0 + RB; if (r1 > n) r1 = n;
  int nr = r1 - r0;
  int cnt = bcnt[b];
  const int2* src = mid + (size_t)b * CAPB;

  psum[tid] = (tid < b && tid < nb) ? bcnt[tid] : 0;
  __syncthreads();
  for (int off = 128; off > 0; off >>= 1) {
    if (tid < off) psum[tid] += psum[tid + off];
    __syncthreads();
  }
  int bas = psum[0];
  __syncthreads();

  for (int r = tid; r < RB; r += 256) rcnt[r] = 0;
  __syncthreads();
  for (int i = tid; i < cnt; i += 256)
    atomicAdd(&rcnt[((unsigned)src[i].x) >> 17], 1);
  __syncthreads();
  int s2 = rcnt[2 * tid] + rcnt[2 * tid + 1];
  psum[tid] = s2;
  __syncthreads();
  for (int off = 1; off < 256; off <<= 1) {
    int u = (tid >= off) ? psum[tid - off] : 0;
    __syncthreads();
    psum[tid] += u;
    __syncthreads();
  }
  int ex = (tid > 0) ? psum[tid - 1] : 0;
  rofs[2 * tid]     = ex;
  rofs[2 * tid + 1] = ex + rcnt[2 * tid];
  __syncthreads();
  for (int r = tid; r < nr; r += 256) rptr[r0 + r] = bas + rofs[r];
  if (b == nb - 1 && tid == 0) rptr[n] = bas + cnt;
  for (int i = tid; i < cnt; i += 256) {
    int2 ed = src[i];
    int rl  = ((unsigned)ed.x) >> 17;
    int col = ed.x & 0x1FFFF;
    int p = atomicAdd(&rofs[rl], 1);
    st[p] = make_int2(col, ed.y);
  }
  __syncthreads();
  for (int i = tid; i < cnt; i += 256) {
    int2 ed = st[i];
    ecols[bas + i] = ed.x << 8;          // byte offset into fp16 x-table
    ewh[bas + i]   = __float2half(__int_as_float(ed.y));
  }
}

// ---- SpMM: wide gathers (16B/lane, 4 edges per wave instr), 2 in flight --
// lane-quarter q = lane>>4 owns edge i+q; lane holds 8 feats (fl = lane&15).
__global__ __launch_bounds__(256) void spmm_kernel(
    const int* __restrict__ rptr, const int* __restrict__ ecols,
    const __half* __restrict__ ewh,
    const __half* __restrict__ xin, __half* __restrict__ xout, int n) {
  int lane = threadIdx.x & 63;
  int q  = lane >> 4;             // edge within group-of-4
  int fl = lane & 15;             // 16 B feature chunk within 256 B row
  int row = (blockIdx.x << 2) + (threadIdx.x >> 6);
  if (row >= n) return;
  int s = rptr[row], e = rptr[row + 1];
  float a00 = 0.f, a01 = 0.f, a02 = 0.f, a03 = 0.f;
  float a04 = 0.f, a05 = 0.f, a06 = 0.f, a07 = 0.f;
  float b00 = 0.f, b01 = 0.f, b02 = 0.f, b03 = 0.f;
  float b04 = 0.f, b05 = 0.f, b06 = 0.f, b07 = 0.f;
  const char* xb = (const char*)xin;
  union V { int4 i4; __half2 h2[4]; };

#define UNPACK_FMA(U, W, P)                                                   \
  {                                                                           \
    float2 f0 = __half22float2((U).h2[0]);                                    \
    float2 f1 = __half22float2((U).h2[1]);                                    \
    float2 f2 = __half22float2((U).h2[2]);                                    \
    float2 f3 = __half22float2((U).h2[3]);                                    \
    P##0 = fmaf((W), f0.x, P##0); P##1 = fmaf((W), f0.y, P##1);               \
    P##2 = fmaf((W), f1.x, P##2); P##3 = fmaf((W), f1.y, P##3);               \
    P##4 = fmaf((W), f2.x, P##4); P##5 = fmaf((W), f2.y, P##5);               \
    P##6 = fmaf((W), f3.x, P##6); P##7 = fmaf((W), f3.y, P##7);               \
  }

  int i = s;
  for (; i + 7 < e; i += 8) {      // 8 edges = 2 wide gathers in flight
    int   ca = ecols[i + q];
    int   cb = ecols[i + 4 + q];
    float wa = __half2float(ewh[i + q]);
    float wb = __half2float(ewh[i + 4 + q]);
    V va, vb;
    va.i4 = *(const int4*)(xb + (size_t)(unsigned)ca + (fl << 4));
    vb.i4 = *(const int4*)(xb + (size_t)(unsigned)cb + (fl << 4));
    UNPACK_FMA(va, wa, a0);
    UNPACK_FMA(vb, wb, b0);
  }
  for (; i < e; i += 4) {          // tail groups of <=4 edges (predicated)
    int idx = i + q;
    bool ok = idx < e;
    int   c = ecols[ok ? idx : e - 1];
    float w = ok ? __half2float(ewh[idx]) : 0.f;
    V v;
    v.i4 = *(const int4*)(xb + (size_t)(unsigned)c + (fl << 4));
    UNPACK_FMA(v, w, a0);
  }
#undef UNPACK_FMA

  a00 += b00; a01 += b01; a02 += b02; a03 += b03;
  a04 += b04; a05 += b05; a06 += b06; a07 += b07;
#define RED(X) X += __shfl_xor(X, 16, 64); X += __shfl_xor(X, 32, 64);
  RED(a00) RED(a01) RED(a02) RED(a03) RED(a04) RED(a05) RED(a06) RED(a07)
#undef RED
  if (q == 0) {
    union V o;
    o.h2[0] = __float22half2_rn(make_float2(a00, a01));
    o.h2[1] = __float22half2_rn(make_float2(a02, a03));
    o.h2[2] = __float22half2_rn(make_float2(a04, a05));
    o.h2[3] = __float22half2_rn(make_float2(a06, a07));
    *(int4*)((char*)xout + ((size_t)row << 8) + (fl << 4)) = o.i4;
  }
}

__global__ void f32_to_f16(const float2* __restrict__ in, __half2* __restrict__ out, int n2) {
  int i = blockIdx.x * blockDim.x + threadIdx.x;
  if (i < n2) out[i] = __float22half2_rn(in[i]);
}

// ---- Linear via MFMA 16x16x32 f16: out = X(fp16) @ Wh^T + b --------------
__global__ __launch_bounds__(256) void linear_mfma(
    const __half* __restrict__ xin, const __half* __restrict__ Wh,
    const float* __restrict__ b, float* __restrict__ out, int n) {
  int lane = threadIdx.x & 63;
  int wv   = threadIdx.x >> 6;
  int rbase = blockIdx.x * 64 + wv * 16;
  if (rbase >= n) return;
  int arow = rbase + (lane & 15);
  if (arow >= n) arow = n - 1;               // clamp; padded rows discarded
  int koff = (lane >> 4) * 8;                // 8 consecutive k per lane

  half8 a0 = *(const half8*)(xin + (size_t)arow * F + 0  + koff);
  half8 a1 = *(const half8*)(xin + (size_t)arow * F + 32 + koff);
  half8 a2 = *(const half8*)(xin + (size_t)arow * F + 64 + koff);
  half8 a3 = *(const half8*)(xin + (size_t)arow * F + 96 + koff);

  int drow0 = rbase + (lane >> 4) * 4;       // D: row=(l>>4)*4+m, col=l&15
  int dcol  = lane & 15;
#pragma unroll
  for (int jt = 0; jt < 8; ++jt) {
    const __half* wrow = Wh + (size_t)(jt * 16 + (lane & 15)) * F + koff;
    half8 b0 = *(const half8*)(wrow + 0);
    half8 b1 = *(const half8*)(wrow + 32);
    half8 b2 = *(const half8*)(wrow + 64);
    half8 b3 = *(const half8*)(wrow + 96);
    f32x4 acc = {0.f, 0.f, 0.f, 0.f};
    acc = __builtin_amdgcn_mfma_f32_16x16x32_f16(a0, b0, acc, 0, 0, 0);
    acc = __builtin_amdgcn_mfma_f32_16x16x32_f16(a1, b1, acc, 0, 0, 0);
    acc = __builtin_amdgcn_mfma_f32_16x16x32_f16(a2, b2, acc, 0, 0, 0);
    acc = __builtin_amdgcn_mfma_f32_16x16x32_f16(a3, b3, acc, 0, 0, 0);
    float bias = b[jt * 16 + dcol];
#pragma unroll
    for (int m = 0; m < 4; ++m) {
      int r = drow0 + m;
      if (r < n) out[(size_t)r * F + jt * 16 + dcol] = acc[m] + bias;
    }
  }
}

extern "C" void kernel_launch(void* const* d_in, const int* in_sizes, int n_in,
                              void* d_out, int out_size, void* d_ws, size_t ws_size,
                              hipStream_t stream) {
  const float* x    = (const float*)d_in[0];
  const int*   erow = (const int*)d_in[1];
  const int*   ecol = (const int*)d_in[2];
  const float* ew   = (const float*)d_in[3];
  const float* W    = (const float*)d_in[4];
  const float* b    = (const float*)d_in[5];
  float* out = (float*)d_out;

  const int N = in_sizes[0] / F;
  const int E = in_sizes[1];

  char* ws = (char*)d_ws;
  size_t off = 0;
  int*    ecols = (int*)(ws + off);    off += (size_t)E * 4;
  __half* ewh   = (__half*)(ws + off); off += (size_t)E * 2;
  off = (off + 255) & ~(size_t)255;
  int*   rptr   = (int*)(ws + off);    off += (size_t)(N + 1) * 4;
  int*   bcnt   = (int*)(ws + off);    off += MAXB * 4;
  off = (off + 255) & ~(size_t)255;
  __half* Wh    = (__half*)(ws + off); off += (size_t)F * F * 2;
  off = (off + 255) & ~(size_t)255;
  // big region (51.2 MB): hosts mid (nb*CAPB int2 <= 28.9 MB) during the CSR
  // build, then the fp16 ping-pong buffers A,B (25.6 MB each). mid is fully
  // consumed by csr_sort before f32_to_f16 writes bufB (stream-serial).
  __half* bufA = (__half*)(ws + off);
  __half* bufB = (__half*)(ws + off + (size_t)N * F * 2);
  int2*   mid  = (int2*)bufA;

  const int BK = 256;
  int nb = (N + RB - 1) >> RB_LOG;     // 512-row buckets (<= MAXB)
  int nwb = (F * F + BK - 1) / BK;     // W-conversion blocks

  // --- prep (zero bcnt + W->fp16) and bucket-native CSR build
  prep_kernel<<<nwb + 1, BK, 0, stream>>>(W, Wh, F * F, bcnt, nwb);
  bucket_scatter<<<(E + CH - 1) / CH, 256, 0, stream>>>(erow, ecol, ew, bcnt, mid, E, nb);
  csr_sort<<<nb, 256, 0, stream>>>(mid, bcnt, rptr, ecols, ewh, N, nb);

  // --- convert x to fp16, then 4 SpMM iterations (ping-pong B <-> A)
  int n2 = N * (F / 2);
  f32_to_f16<<<(n2 + BK - 1) / BK, BK, 0, stream>>>((const float2*)x, (__half2*)bufB, n2);
  int spmm_grid = (N + 3) / 4;
  spmm_kernel<<<spmm_grid, 256, 0, stream>>>(rptr, ecols, ewh, bufB, bufA, N);
  spmm_kernel<<<spmm_grid, 256, 0, stream>>>(rptr, ecols, ewh, bufA, bufB, N);
  spmm_kernel<<<spmm_grid, 256, 0, stream>>>(rptr, ecols, ewh, bufB, bufA, N);
  spmm_kernel<<<spmm_grid, 256, 0, stream>>>(rptr, ecols, ewh, bufA, bufB, N);

  // --- Linear: bufB (fp16) @ Wh^T + b -> out (fp32), via MFMA
  linear_mfma<<<(N + 63) / 64, 256, 0, stream>>>(bufB, Wh, b, out, N);
}

// Round 14
// 544.589 us; speedup vs baseline: 4.5853x; 1.0264x over previous
//
#include <hip/hip_runtime.h>
#include <hip/hip_fp16.h>

// ---------------------------------------------------------------------------
// sglayer: k=4 iterations of SpMM (COO segment-sum) then Linear(128->128).
// CSR build (bucket-native): prep (zero bcnt + W->fp16) -> phase A bucket
// partition (512 thr) -> phase B per-bucket LDS sort (512 thr) -> split
// col[byteoff]/w[fp16].
// SpMM: fp16 storage / fp32 accumulate, 1 wave/row, WIDE gathers
// (dwordx4/lane, lane-quarter per edge), 2 in flight (8 edges/iter) —
// empirically the sweet spot: the kernel sits on the per-CU miss-transaction
// rate wall (~49 misses/us/CU), so deeper unrolls only cost occupancy.
// Linear: MFMA 16x16x32 f16.
// ---------------------------------------------------------------------------

#define F 128
#define CH 2048          // edges staged per block in phase A
#define MAXB 256         // max coarse buckets (N <= 131072)
#define RB_LOG 9         // rows per bucket = 512
#define RB (1 << RB_LOG)
#define CAPB 18432       // bucket region capacity (mean 16384, +16 sigma)

typedef _Float16 half8 __attribute__((ext_vector_type(8)));
typedef float f32x4 __attribute__((ext_vector_type(4)));

// ---- prep: zero bcnt (block nwb) + W -> fp16 (blocks 0..nwb-1) -----------
__global__ void prep_kernel(const float* __restrict__ W, __half* __restrict__ Wh,
                            int nw, int* __restrict__ bcnt, int nwb) {
  int blk = blockIdx.x;
  if (blk == nwb) {
    int t = threadIdx.x;
    if (t < MAXB) bcnt[t] = 0;
  } else {
    int i = blk * 256 + threadIdx.x;
    if (i < nw) Wh[i] = __float2half(W[i]);
  }
}

// ---- Phase A: LDS-staged partition into fixed-capacity bucket regions ----
// mid[b*CAPB + k] entry: ((row & 511) << 17) | col , weight fp32 bits
__global__ __launch_bounds__(512) void bucket_scatter(
    const int* __restrict__ erow, const int* __restrict__ ecol,
    const float* __restrict__ ew, int* __restrict__ bcnt,
    int2* __restrict__ mid, int e, int nb) {
  __shared__ int  rowv[CH];                // 8 KB raw rows
  __shared__ int2 cw[CH];                  // 16 KB raw (col, wbits)
  __shared__ int2 stage[CH];               // 16 KB bucket-grouped
  __shared__ unsigned short sbid[CH];      // 4 KB
  __shared__ int cnt[MAXB], lstart[MAXB], gbase[MAXB], cnt2[MAXB];
  __shared__ int ps[256];
  int tid = threadIdx.x;                   // 0..511
  int base = blockIdx.x * CH;
  int tot = e - base; if (tot > CH) tot = CH;
  for (int t = tid; t < nb; t += 512) { cnt[t] = 0; cnt2[t] = 0; }
  __syncthreads();
  for (int j = tid; j < tot; j += 512) {
    int i = base + j;
    int r = erow[i];
    rowv[j] = r;
    cw[j] = make_int2(ecol[i], __float_as_int(ew[i]));
    atomicAdd(&cnt[r >> RB_LOG], 1);
  }
  __syncthreads();
  // exclusive scan of cnt[0..nb) on the first 256 threads
  int v = 0;
  if (tid < 256) { v = (tid < nb) ? cnt[tid] : 0; ps[tid] = v; }
  __syncthreads();
  for (int off = 1; off < 256; off <<= 1) {
    int u = 0;
    if (tid < 256 && tid >= off) u = ps[tid - off];
    __syncthreads();
    if (tid < 256) ps[tid] += u;
    __syncthreads();
  }
  if (tid < nb) lstart[tid] = ps[tid] - v;
  __syncthreads();
  for (int t = tid; t < nb; t += 512)
    if (cnt[t] > 0) gbase[t] = atomicAdd(&bcnt[t], cnt[t]);
  __syncthreads();
  for (int j = tid; j < tot; j += 512) {
    int r = rowv[j];
    int bb = r >> RB_LOG;
    int k = atomicAdd(&cnt2[bb], 1);
    int p = lstart[bb] + k;
    stage[p] = make_int2(((r & (RB - 1)) << 17) | cw[j].x, cw[j].y);
    sbid[p] = (unsigned short)bb;
  }
  __syncthreads();
  for (int j = tid; j < tot; j += 512) {   // coalesced bucket runs
    int bb = sbid[j];
    mid[(size_t)bb * CAPB + gbase[bb] + (j - lstart[bb])] = stage[j];
  }
}

// ---- Phase B: per-bucket base reduce, LDS hist+scan (rptr), count sort ---
// outputs split arrays: ecols[i] = col byte-offset, ewh[i] = fp16 weight
__global__ __launch_bounds__(512) void csr_sort(
    const int2* __restrict__ mid, const int* __restrict__ bcnt,
    int* __restrict__ rptr, int* __restrict__ ecols, __half* __restrict__ ewh,
    int n, int nb) {
  __shared__ int rcnt[RB];                 // 2 KB
  __shared__ int rofs[RB];                 // 2 KB (exclusive ofs, then cursor)
  __shared__ int ps[RB];                   // 2 KB scan scratch
  __shared__ int2 st[CAPB];                // 144 KB
  int b = blockIdx.x, tid = threadIdx.x;   // 0..511
  int r0 = b << RB_LOG;
  int r1 = r0 + RB; if (r1 > n) r1 = n;
  int nr = r1 - r0;
  int cntE = bcnt[b];
  const int2* src = mid + (size_t)b * CAPB;

  // base = sum of bcnt[t < b]  (tree reduce over 512 slots)
  ps[tid] = (tid < b) ? bcnt[tid] : 0;
  __syncthreads();
  for (int off = 256; off > 0; off >>= 1) {
    if (tid < off) ps[tid] += ps[tid + off];
    __syncthreads();
  }
  int bas = ps[0];
  __syncthreads();

  rcnt[tid] = 0;                           // one per row (RB == 512)
  __syncthreads();
  for (int i = tid; i < cntE; i += 512)
    atomicAdd(&rcnt[((unsigned)src[i].x) >> 17], 1);
  __syncthreads();
  // 512-wide Hillis-Steele inclusive scan -> exclusive offsets
  int v = rcnt[tid];
  ps[tid] = v;
  __syncthreads();
  for (int off = 1; off < 512; off <<= 1) {
    int u = (tid >= off) ? ps[tid - off] : 0;
    __syncthreads();
    ps[tid] += u;
    __syncthreads();
  }
  rofs[tid] = ps[tid] - v;                 // exclusive prefix
  __syncthreads();
  // rptr for this bucket's rows
  if (tid < nr) rptr[r0 + tid] = bas + rofs[tid];
  if (b == nb - 1 && tid == 0) rptr[n] = bas + cntE;
  __syncthreads();                         // protect rofs before cursor use
  // counting sort into LDS (rofs doubles as cursor)
  for (int i = tid; i < cntE; i += 512) {
    int2 ed = src[i];
    int rl  = ((unsigned)ed.x) >> 17;
    int col = ed.x & 0x1FFFF;
    int p = atomicAdd(&rofs[rl], 1);
    st[p] = make_int2(col, ed.y);
  }
  __syncthreads();
  for (int i = tid; i < cntE; i += 512) {
    int2 ed = st[i];
    ecols[bas + i] = ed.x << 8;          // byte offset into fp16 x-table
    ewh[bas + i]   = __float2half(__int_as_float(ed.y));
  }
}

// ---- SpMM: wide gathers (16B/lane, 4 edges per wave instr), 2 in flight --
// lane-quarter q = lane>>4 owns edge i+q; lane holds 8 feats (fl = lane&15).
__global__ __launch_bounds__(256) void spmm_kernel(
    const int* __restrict__ rptr, const int* __restrict__ ecols,
    const __half* __restrict__ ewh,
    const __half* __restrict__ xin, __half* __restrict__ xout, int n) {
  int lane = threadIdx.x & 63;
  int q  = lane >> 4;             // edge within group-of-4
  int fl = lane & 15;             // 16 B feature chunk within 256 B row
  int row = (blockIdx.x << 2) + (threadIdx.x >> 6);
  if (row >= n) return;
  int s = rptr[row], e = rptr[row + 1];
  float a00 = 0.f, a01 = 0.f, a02 = 0.f, a03 = 0.f;
  float a04 = 0.f, a05 = 0.f, a06 = 0.f, a07 = 0.f;
  float b00 = 0.f, b01 = 0.f, b02 = 0.f, b03 = 0.f;
  float b04 = 0.f, b05 = 0.f, b06 = 0.f, b07 = 0.f;
  const char* xb = (const char*)xin;
  union V { int4 i4; __half2 h2[4]; };

#define UNPACK_FMA(U, W, P)                                                   \
  {                                                                           \
    float2 f0 = __half22float2((U).h2[0]);                                    \
    float2 f1 = __half22float2((U).h2[1]);                                    \
    float2 f2 = __half22float2((U).h2[2]);                                    \
    float2 f3 = __half22float2((U).h2[3]);                                    \
    P##0 = fmaf((W), f0.x, P##0); P##1 = fmaf((W), f0.y, P##1);               \
    P##2 = fmaf((W), f1.x, P##2); P##3 = fmaf((W), f1.y, P##3);               \
    P##4 = fmaf((W), f2.x, P##4); P##5 = fmaf((W), f2.y, P##5);               \
    P##6 = fmaf((W), f3.x, P##6); P##7 = fmaf((W), f3.y, P##7);               \
  }

  int i = s;
  for (; i + 7 < e; i += 8) {      // 8 edges = 2 wide gathers in flight
    int   ca = ecols[i + q];
    int   cb = ecols[i + 4 + q];
    float wa = __half2float(ewh[i + q]);
    float wb = __half2float(ewh[i + 4 + q]);
    V va, vb;
    va.i4 = *(const int4*)(xb + (size_t)(unsigned)ca + (fl << 4));
    vb.i4 = *(const int4*)(xb + (size_t)(unsigned)cb + (fl << 4));
    UNPACK_FMA(va, wa, a0);
    UNPACK_FMA(vb, wb, b0);
  }
  for (; i < e; i += 4) {          // tail groups of <=4 edges (predicated)
    int idx = i + q;
    bool ok = idx < e;
    int   c = ecols[ok ? idx : e - 1];
    float w = ok ? __half2float(ewh[idx]) : 0.f;
    V v;
    v.i4 = *(const int4*)(xb + (size_t)(unsigned)c + (fl << 4));
    UNPACK_FMA(v, w, a0);
  }
#undef UNPACK_FMA

  a00 += b00; a01 += b01; a02 += b02; a03 += b03;
  a04 += b04; a05 += b05; a06 += b06; a07 += b07;
#define RED(X) X += __shfl_xor(X, 16, 64); X += __shfl_xor(X, 32, 64);
  RED(a00) RED(a01) RED(a02) RED(a03) RED(a04) RED(a05) RED(a06) RED(a07)
#undef RED
  if (q == 0) {
    union V o;
    o.h2[0] = __float22half2_rn(make_float2(a00, a01));
    o.h2[1] = __float22half2_rn(make_float2(a02, a03));
    o.h2[2] = __float22half2_rn(make_float2(a04, a05));
    o.h2[3] = __float22half2_rn(make_float2(a06, a07));
    *(int4*)((char*)xout + ((size_t)row << 8) + (fl << 4)) = o.i4;
  }
}

__global__ void f32_to_f16(const float2* __restrict__ in, __half2* __restrict__ out, int n2) {
  int i = blockIdx.x * blockDim.x + threadIdx.x;
  if (i < n2) out[i] = __float22half2_rn(in[i]);
}

// ---- Linear via MFMA 16x16x32 f16: out = X(fp16) @ Wh^T + b --------------
__global__ __launch_bounds__(256) void linear_mfma(
    const __half* __restrict__ xin, const __half* __restrict__ Wh,
    const float* __restrict__ b, float* __restrict__ out, int n) {
  int lane = threadIdx.x & 63;
  int wv   = threadIdx.x >> 6;
  int rbase = blockIdx.x * 64 + wv * 16;
  if (rbase >= n) return;
  int arow = rbase + (lane & 15);
  if (arow >= n) arow = n - 1;               // clamp; padded rows discarded
  int koff = (lane >> 4) * 8;                // 8 consecutive k per lane

  half8 a0 = *(const half8*)(xin + (size_t)arow * F + 0  + koff);
  half8 a1 = *(const half8*)(xin + (size_t)arow * F + 32 + koff);
  half8 a2 = *(const half8*)(xin + (size_t)arow * F + 64 + koff);
  half8 a3 = *(const half8*)(xin + (size_t)arow * F + 96 + koff);

  int drow0 = rbase + (lane >> 4) * 4;       // D: row=(l>>4)*4+m, col=l&15
  int dcol  = lane & 15;
#pragma unroll
  for (int jt = 0; jt < 8; ++jt) {
    const __half* wrow = Wh + (size_t)(jt * 16 + (lane & 15)) * F + koff;
    half8 b0 = *(const half8*)(wrow + 0);
    half8 b1 = *(const half8*)(wrow + 32);
    half8 b2 = *(const half8*)(wrow + 64);
    half8 b3 = *(const half8*)(wrow + 96);
    f32x4 acc = {0.f, 0.f, 0.f, 0.f};
    acc = __builtin_amdgcn_mfma_f32_16x16x32_f16(a0, b0, acc, 0, 0, 0);
    acc = __builtin_amdgcn_mfma_f32_16x16x32_f16(a1, b1, acc, 0, 0, 0);
    acc = __builtin_amdgcn_mfma_f32_16x16x32_f16(a2, b2, acc, 0, 0, 0);
    acc = __builtin_amdgcn_mfma_f32_16x16x32_f16(a3, b3, acc, 0, 0, 0);
    float bias = b[jt * 16 + dcol];
#pragma unroll
    for (int m = 0; m < 4; ++m) {
      int r = drow0 + m;
      if (r < n) out[(size_t)r * F + jt * 16 + dcol] = acc[m] + bias;
    }
  }
}

extern "C" void kernel_launch(void* const* d_in, const int* in_sizes, int n_in,
                              void* d_out, int out_size, void* d_ws, size_t ws_size,
                              hipStream_t stream) {
  const float* x    = (const float*)d_in[0];
  const int*   erow = (const int*)d_in[1];
  const int*   ecol = (const int*)d_in[2];
  const float* ew   = (const float*)d_in[3];
  const float* W    = (const float*)d_in[4];
  const float* b    = (const float*)d_in[5];
  float* out = (float*)d_out;

  const int N = in_sizes[0] / F;
  const int E = in_sizes[1];

  char* ws = (char*)d_ws;
  size_t off = 0;
  int*    ecols = (int*)(ws + off);    off += (size_t)E * 4;
  __half* ewh   = (__half*)(ws + off); off += (size_t)E * 2;
  off = (off + 255) & ~(size_t)255;
  int*   rptr   = (int*)(ws + off);    off += (size_t)(N + 1) * 4;
  int*   bcnt   = (int*)(ws + off);    off += MAXB * 4;
  off = (off + 255) & ~(size_t)255;
  __half* Wh    = (__half*)(ws + off); off += (size_t)F * F * 2;
  off = (off + 255) & ~(size_t)255;
  // big region (51.2 MB): hosts mid (nb*CAPB int2 <= 28.9 MB) during the CSR
  // build, then the fp16 ping-pong buffers A,B (25.6 MB each). mid is fully
  // consumed by csr_sort before f32_to_f16 writes bufB (stream-serial).
  __half* bufA = (__half*)(ws + off);
  __half* bufB = (__half*)(ws + off + (size_t)N * F * 2);
  int2*   mid  = (int2*)bufA;

  const int BK = 256;
  int nb = (N + RB - 1) >> RB_LOG;     // 512-row buckets (<= MAXB)
  int nwb = (F * F + BK - 1) / BK;     // W-conversion blocks

  // --- prep (zero bcnt + W->fp16) and bucket-native CSR build
  prep_kernel<<<nwb + 1, BK, 0, stream>>>(W, Wh, F * F, bcnt, nwb);
  bucket_scatter<<<(E + CH - 1) / CH, 512, 0, stream>>>(erow, ecol, ew, bcnt, mid, E, nb);
  csr_sort<<<nb, 512, 0, stream>>>(mid, bcnt, rptr, ecols, ewh, N, nb);

  // --- convert x to fp16, then 4 SpMM iterations (ping-pong B <-> A)
  int n2 = N * (F / 2);
  f32_to_f16<<<(n2 + BK - 1) / BK, BK, 0, stream>>>((const float2*)x, (__half2*)bufB, n2);
  int spmm_grid = (N + 3) / 4;
  spmm_kernel<<<spmm_grid, 256, 0, stream>>>(rptr, ecols, ewh, bufB, bufA, N);
  spmm_kernel<<<spmm_grid, 256, 0, stream>>>(rptr, ecols, ewh, bufA, bufB, N);
  spmm_kernel<<<spmm_grid, 256, 0, stream>>>(rptr, ecols, ewh, bufB, bufA, N);
  spmm_kernel<<<spmm_grid, 256, 0, stream>>>(rptr, ecols, ewh, bufA, bufB, N);

  // --- Linear: bufB (fp16) @ Wh^T + b -> out (fp32), via MFMA
  linear_mfma<<<(N + 63) / 64, 256, 0, stream>>>(bufB, Wh, b, out, N);
}